// Round 12
// baseline (108.371 us; speedup 1.0000x reference)
//
#include <hip/hip_runtime.h>

#define T_SEQ 2048
#define NH    16
#define HD    64
#define DIM   1024
#define WIN   256
#define REP_A 6   // attn repetitions (instrumentation; outputs stored每rep -> no DCE)
#define REP_G 5   // proj repetitions (instrumentation)

typedef __attribute__((ext_vector_type(4))) float f32x4;
typedef __attribute__((ext_vector_type(8))) short s16x8;
typedef unsigned short u16;

static __device__ __forceinline__ u16 f2bf(float f) {
    unsigned u = __builtin_bit_cast(unsigned, f);
    u += 0x7fff + ((u >> 16) & 1);   // RNE; inputs finite
    return (u16)(u >> 16);
}

static __device__ __forceinline__ int fV(int d) { return (d & 7) ^ ((d >> 3) & 7); }

static __device__ __forceinline__ void gload16(const void* g, void* l) {
    __builtin_amdgcn_global_load_lds(
        (const __attribute__((address_space(1))) unsigned int*)g,
        (__attribute__((address_space(3))) unsigned int*)l, 16, 0, 0);
}

// ---------------------------------------------------------------------------
// conv (unchanged from R11): one streaming pass producing all bf16 operands.
// ---------------------------------------------------------------------------
__global__ __launch_bounds__(256) void conv_kernel(const float* __restrict__ W,
                                                   u16* __restrict__ Wt,
                                                   const float* __restrict__ kg,
                                                   u16* __restrict__ Kc,
                                                   const float* __restrict__ vg,
                                                   u16* __restrict__ Vt) {
    __shared__ float sT[64][69];
    const int bid = (int)blockIdx.x;
    const int t   = threadIdx.x;

    if (bid < 256) {
        const int k0 = (bid & 15) * 64;
        const int n0 = (bid >> 4) * 64;
#pragma unroll
        for (int i = 0; i < 4; ++i) {
            const int idx = i * 256 + t;
            const int kr = idx >> 4, c4 = (idx & 15) * 4;
            float4 v = *(const float4*)(W + (size_t)(k0 + kr) * DIM + n0 + c4);
            sT[kr][c4] = v.x; sT[kr][c4 + 1] = v.y; sT[kr][c4 + 2] = v.z; sT[kr][c4 + 3] = v.w;
        }
        __syncthreads();
#pragma unroll
        for (int i = 0; i < 2; ++i) {
            const int idx = i * 256 + t;
            const int nr = idx >> 3, ch = (idx & 7) * 8;
            s16x8 o;
#pragma unroll
            for (int e = 0; e < 8; ++e) o[e] = f2bf(sT[ch + e][nr]);
            *(s16x8*)(Wt + (size_t)(n0 + nr) * DIM + k0 + ch) = o;
        }
    } else if (bid < 768) {
        const int vt  = bid - 256;
        const int h   = vt >> 5;
        const int kt0 = (vt & 31) * 64;
        const float* src = vg + ((size_t)h * T_SEQ + kt0) * HD;
#pragma unroll
        for (int i = 0; i < 4; ++i) {
            const int idx = i * 256 + t;
            const int kr = idx >> 4, c4 = (idx & 15) * 4;
            float4 v = *(const float4*)(src + (size_t)kr * HD + c4);
            sT[kr][c4] = v.x; sT[kr][c4 + 1] = v.y; sT[kr][c4 + 2] = v.z; sT[kr][c4 + 3] = v.w;
        }
        __syncthreads();
#pragma unroll
        for (int i = 0; i < 2; ++i) {
            const int idx = i * 256 + t;
            const int nr = idx >> 3, ch = (idx & 7) * 8;
            s16x8 o;
#pragma unroll
            for (int e = 0; e < 8; ++e) o[e] = f2bf(sT[ch + e][nr]);
            *(s16x8*)(Vt + ((size_t)h * HD + nr) * T_SEQ + kt0 + ch) = o;
        }
    } else {
        const int kb = bid - 768;
        const float* src = kg + (size_t)kb * 8192;
        u16* dst = Kc + (size_t)kb * 8192;
#pragma unroll
        for (int i = 0; i < 4; ++i) {
            const int off = i * 2048 + t * 8;
            float4 a = *(const float4*)(src + off);
            float4 b = *(const float4*)(src + off + 4);
            s16x8 o;
            o[0] = f2bf(a.x); o[1] = f2bf(a.y); o[2] = f2bf(a.z); o[3] = f2bf(a.w);
            o[4] = f2bf(b.x); o[5] = f2bf(b.y); o[6] = f2bf(b.z); o[7] = f2bf(b.w);
            *(s16x8*)(dst + off) = o;
        }
    }
}

// ---------------------------------------------------------------------------
// attn (R11 verbatim) x REP_A. Output stored each rep (identical values) so
// every rep's compute is live. Rep boundary: last iter already drains
// vmcnt(0) + end barrier -> safe to re-STAGE buf0.
// ---------------------------------------------------------------------------
__global__ __launch_bounds__(256) void attn_kernel(const float* __restrict__ qg,
                                                   const u16* __restrict__ Kc,
                                                   const u16* __restrict__ Vt,
                                                   u16* __restrict__ y) {
    __shared__ __align__(16) char sK[2][8192];
    __shared__ __align__(16) char sV[2][8192];
    __shared__ __align__(16) char sP[4][2048];

    const int ab   = (int)blockIdx.x;
    const int swzb = (ab & 7) * 64 + (ab >> 3);
    const int t    = threadIdx.x;
    const int lane = t & 63;
    const int w    = t >> 6;
    const int q0   = (swzb & 31) * 64;
    const int h    = swzb >> 5;

    const u16* Kh = Kc + (size_t)h * T_SEQ * HD;
    const u16* Vh = Vt + (size_t)h * HD * T_SEQ;

    const int lr = lane & 15;
    const int lg = lane >> 4;

    s16x8 qf[2];
    {
        const float* qrow = qg + ((size_t)h * T_SEQ + q0 + w * 16 + lr) * HD + lg * 8;
#pragma unroll
        for (int s = 0; s < 2; ++s) {
            float4 a = *(const float4*)(qrow + 32 * s);
            float4 b = *(const float4*)(qrow + 32 * s + 4);
            s16x8 f;
            f[0] = f2bf(a.x); f[1] = f2bf(a.y); f[2] = f2bf(a.z); f[3] = f2bf(a.w);
            f[4] = f2bf(b.x); f[5] = f2bf(b.y); f[6] = f2bf(b.z); f[7] = f2bf(b.w);
            qf[s] = f;
        }
    }

    int lo = q0 - (WIN - 1);
    if (lo < 0) lo = 0;
    const int kc0 = lo & ~63;
    const int nc  = (q0 - kc0) / 64 + 1;

    const int sRow8 = lane >> 3;
    const int sCh   = lane & 7;

#define STAGE(buf, kc)                                                              \
    do {                                                                            \
        _Pragma("unroll") for (int j = 0; j < 2; ++j) {                             \
            const int s_  = j * 4 + w;                                              \
            const int row = s_ * 8 + sRow8;                                         \
            gload16(Kh + (size_t)((kc) + row) * HD + ((sCh ^ (row & 7)) << 3),      \
                    sK[buf] + s_ * 1024);                                           \
            gload16(Vh + (size_t)row * T_SEQ + (kc) + ((sCh ^ fV(row)) << 3),       \
                    sV[buf] + s_ * 1024);                                           \
        }                                                                           \
    } while (0)

#pragma unroll 1
    for (int rep = 0; rep < REP_A; ++rep) {
        f32x4 o[4];
#pragma unroll
        for (int i = 0; i < 4; ++i) o[i] = (f32x4){0.f, 0.f, 0.f, 0.f};
        float lsum[4] = {0.f, 0.f, 0.f, 0.f};

        STAGE(0, kc0);

        for (int ic = 0; ic < nc; ++ic) {
            const int kc = kc0 + ic * 64;
            const int cb = ic & 1;
            if (ic + 1 < nc) {
                STAGE(cb ^ 1, kc + 64);
                asm volatile("s_waitcnt vmcnt(4)" ::: "memory");
            } else {
                asm volatile("s_waitcnt vmcnt(0)" ::: "memory");
            }
            __builtin_amdgcn_s_barrier();

            char* pw = sP[w];
#pragma unroll
            for (int kt = 0; kt < 4; ++kt) {
                const int krow = kt * 16 + lr;
                const int kswz = (krow & 7) << 4;
                s16x8 kf0 = *(const s16x8*)(sK[cb] + krow * 128 + ((lg * 16) ^ kswz));
                s16x8 kf1 = *(const s16x8*)(sK[cb] + krow * 128 + ((lg * 16 + 64) ^ kswz));
                f32x4 s = (f32x4){0.f, 0.f, 0.f, 0.f};
                s = __builtin_amdgcn_mfma_f32_16x16x32_bf16(qf[0], kf0, s, 0, 0, 0);
                s = __builtin_amdgcn_mfma_f32_16x16x32_bf16(qf[1], kf1, s, 0, 0, 0);
                const int key = kc + kt * 16 + lr;
#pragma unroll
                for (int r = 0; r < 4; ++r) {
                    const int qrow = q0 + w * 16 + lg * 4 + r;
                    float pv = 0.f;
                    if (key <= qrow && key > qrow - WIN) pv = __expf(s[r] * 0.125f);
                    lsum[r] += pv;
                    const int prow = lg * 4 + r;
                    *(u16*)(pw + prow * 128 + ((kt * 32 + lr * 2) ^ ((prow & 7) << 4))) = f2bf(pv);
                }
            }

            s16x8 pf0 = *(const s16x8*)(pw + lr * 128 + ((lg * 16) ^ ((lr & 7) << 4)));
            s16x8 pf1 = *(const s16x8*)(pw + lr * 128 + ((lg * 16 + 64) ^ ((lr & 7) << 4)));
#pragma unroll
            for (int td = 0; td < 4; ++td) {
                const int drow = td * 16 + lr;
                const int vswz = fV(drow) << 4;
                s16x8 vf0 = *(const s16x8*)(sV[cb] + drow * 128 + ((lg * 16) ^ vswz));
                s16x8 vf1 = *(const s16x8*)(sV[cb] + drow * 128 + ((lg * 16 + 64) ^ vswz));
                o[td] = __builtin_amdgcn_mfma_f32_16x16x32_bf16(pf0, vf0, o[td], 0, 0, 0);
                o[td] = __builtin_amdgcn_mfma_f32_16x16x32_bf16(pf1, vf1, o[td], 0, 0, 0);
            }
            __builtin_amdgcn_s_barrier();
        }

#pragma unroll
        for (int m = 1; m < 16; m <<= 1) {
#pragma unroll
            for (int r = 0; r < 4; ++r) lsum[r] += __shfl_xor(lsum[r], m, 64);
        }
        float rl[4];
#pragma unroll
        for (int r = 0; r < 4; ++r) rl[r] = 1.f / lsum[r];
#pragma unroll
        for (int td = 0; td < 4; ++td)
#pragma unroll
            for (int r = 0; r < 4; ++r)
                y[(size_t)(q0 + w * 16 + lg * 4 + r) * DIM + h * HD + td * 16 + lr] =
                    f2bf(o[td][r] * rl[r]);
    }
#undef STAGE
}

// ---------------------------------------------------------------------------
// proj (R11 verbatim) x REP_G. C stored each rep (identical values) -> no DCE.
// Rep boundary: vmcnt(0) drain + barrier before re-STAGE.
// ---------------------------------------------------------------------------
__global__ __launch_bounds__(256) void proj_kernel(const u16* __restrict__ A,
                                                   const u16* __restrict__ Bt,
                                                   float* __restrict__ out) {
    __shared__ __align__(16) char sA[3][128 * 128];
    __shared__ __align__(16) char sB[3][64 * 128];

    const int t    = threadIdx.x;
    const int lane = t & 63;
    const int w    = t >> 6;
    const int wr   = w >> 1, wc = w & 1;
    const int lr   = lane & 15, lg = lane >> 4;

    const int id   = (int)blockIdx.x;
    const int wgid = (id & 7) * 32 + (id >> 3);
    const int m0   = (wgid >> 4) * 128;
    const int n0   = (wgid & 15) * 64;

    const int sRow = lane >> 3;
    const int sCh  = lane & 7;

#define STAGE(buf, k0)                                                                 \
    do {                                                                               \
        _Pragma("unroll") for (int p = 0; p < 4; ++p) {                                \
            const int pi  = p * 4 + w;                                                 \
            const int row = pi * 8 + sRow;                                             \
            gload16(A + (size_t)(m0 + row) * DIM + (k0) + ((sCh ^ (row & 7)) << 3),    \
                    sA[buf] + pi * 1024);                                              \
        }                                                                              \
        _Pragma("unroll") for (int p = 0; p < 2; ++p) {                                \
            const int pi  = p * 4 + w;                                                 \
            const int row = pi * 8 + sRow;                                             \
            gload16(Bt + (size_t)(n0 + row) * DIM + (k0) + ((sCh ^ (row & 7)) << 3),   \
                    sB[buf] + pi * 1024);                                              \
        }                                                                              \
    } while (0)

#pragma unroll 1
    for (int rep = 0; rep < REP_G; ++rep) {
        f32x4 acc[4][2];
#pragma unroll
        for (int i = 0; i < 4; ++i)
#pragma unroll
            for (int j = 0; j < 2; ++j) acc[i][j] = (f32x4){0.f, 0.f, 0.f, 0.f};

        STAGE(0, 0);
        STAGE(1, 64);

#pragma unroll
        for (int kt = 0; kt < DIM / 64; ++kt) {
            const int cur  = kt % 3;
            const int nxt  = (kt + 2) % 3;
            const int knxt = ((kt + 2) & 15) * 64;

            STAGE(nxt, knxt);
            asm volatile("s_waitcnt vmcnt(12)" ::: "memory");
            __builtin_amdgcn_s_barrier();

            s16x8 af[2][4], bfr[2][2];
#pragma unroll
            for (int kh = 0; kh < 2; ++kh) {
#pragma unroll
                for (int mi = 0; mi < 4; ++mi) {
                    const int row = wr * 64 + mi * 16 + lr;
                    const int cc  = kh * 4 + lg;
                    af[kh][mi] = *(const s16x8*)(sA[cur] + row * 128 + ((cc ^ (row & 7)) << 4));
                }
#pragma unroll
                for (int ni = 0; ni < 2; ++ni) {
                    const int row = wc * 32 + ni * 16 + lr;
                    const int cc  = kh * 4 + lg;
                    bfr[kh][ni] = *(const s16x8*)(sB[cur] + row * 128 + ((cc ^ (row & 7)) << 4));
                }
            }
            __builtin_amdgcn_s_setprio(1);
#pragma unroll
            for (int kh = 0; kh < 2; ++kh)
#pragma unroll
                for (int mi = 0; mi < 4; ++mi)
#pragma unroll
                    for (int ni = 0; ni < 2; ++ni)
                        acc[mi][ni] = __builtin_amdgcn_mfma_f32_16x16x32_bf16(
                            af[kh][mi], bfr[kh][ni], acc[mi][ni], 0, 0, 0);
            __builtin_amdgcn_s_setprio(0);
            __builtin_amdgcn_s_barrier();
        }

        asm volatile("s_waitcnt vmcnt(0)" ::: "memory");  // drain stale tail gloads
        __builtin_amdgcn_s_barrier();                     // WAR: LDS reuse next rep

#pragma unroll
        for (int mi = 0; mi < 4; ++mi)
#pragma unroll
            for (int ni = 0; ni < 2; ++ni)
#pragma unroll
                for (int r = 0; r < 4; ++r)
                    out[(size_t)(m0 + wr * 64 + mi * 16 + lg * 4 + r) * DIM +
                        n0 + wc * 32 + ni * 16 + lr] = acc[mi][ni][r];
    }
#undef STAGE
}

extern "C" void kernel_launch(void* const* d_in, const int* in_sizes, int n_in,
                              void* d_out, int out_size, void* d_ws, size_t ws_size,
                              hipStream_t stream) {
    const float* q = (const float*)d_in[0];
    const float* k = (const float*)d_in[1];
    const float* v = (const float*)d_in[2];
    const float* W = (const float*)d_in[3];
    float* out = (float*)d_out;

    u16* y_bf = (u16*)d_ws;                                   // 2M u16 (4MB)
    u16* Wt   = y_bf + (size_t)T_SEQ * DIM;                   // 1M u16 (2MB)
    u16* Kc   = Wt + (size_t)DIM * DIM;                       // 2M u16 (4MB)
    u16* Vt   = Kc + (size_t)NH * T_SEQ * HD;                 // 2M u16 (4MB)

    conv_kernel<<<1024, 256, 0, stream>>>(W, Wt, k, Kc, v, Vt);
    attn_kernel<<<512, 256, 0, stream>>>(q, Kc, Vt, y_bf);
    proj_kernel<<<256, 256, 0, stream>>>(y_bf, Wt, out);
}

// Round 14
// 37.520 us; speedup vs baseline: 2.8884x; 2.8884x over previous
//
#include <hip/hip_runtime.h>

#define T_SEQ 2048
#define NH    16
#define HD    64
#define DIM   1024
#define WIN   256

typedef __attribute__((ext_vector_type(4))) float f32x4;
typedef __attribute__((ext_vector_type(8))) short s16x8;
typedef unsigned short u16;

static __device__ __forceinline__ u16 f2bf(float f) {
    unsigned u = __builtin_bit_cast(unsigned, f);
    u += 0x7fff + ((u >> 16) & 1);   // RNE; inputs finite
    return (u16)(u >> 16);
}

static __device__ __forceinline__ float exp2fast(float x) {
    return __builtin_amdgcn_exp2f(x);   // v_exp_f32: D = 2^S0
}

static __device__ __forceinline__ int fV(int d) { return (d & 7) ^ ((d >> 3) & 7); }

static __device__ __forceinline__ void gload16(const void* g, void* l) {
    __builtin_amdgcn_global_load_lds(
        (const __attribute__((address_space(1))) unsigned int*)g,
        (__attribute__((address_space(3))) unsigned int*)l, 16, 0, 0);
}

// ---------------------------------------------------------------------------
// conv (unchanged): one streaming pass producing all bf16 operands.
//   [0,256):    W fp32 -> Wt (NxK bf16)        [LDS transpose]
//   [256,768):  V fp32 -> Vt [h][d][key] bf16  [LDS transpose]
//   [768,1024): K fp32 -> Kc bf16              [straight copy]
// ---------------------------------------------------------------------------
__global__ __launch_bounds__(256) void conv_kernel(const float* __restrict__ W,
                                                   u16* __restrict__ Wt,
                                                   const float* __restrict__ kg,
                                                   u16* __restrict__ Kc,
                                                   const float* __restrict__ vg,
                                                   u16* __restrict__ Vt) {
    __shared__ float sT[64][69];
    const int bid = (int)blockIdx.x;
    const int t   = threadIdx.x;

    if (bid < 256) {
        const int k0 = (bid & 15) * 64;
        const int n0 = (bid >> 4) * 64;
#pragma unroll
        for (int i = 0; i < 4; ++i) {
            const int idx = i * 256 + t;
            const int kr = idx >> 4, c4 = (idx & 15) * 4;
            float4 v = *(const float4*)(W + (size_t)(k0 + kr) * DIM + n0 + c4);
            sT[kr][c4] = v.x; sT[kr][c4 + 1] = v.y; sT[kr][c4 + 2] = v.z; sT[kr][c4 + 3] = v.w;
        }
        __syncthreads();
#pragma unroll
        for (int i = 0; i < 2; ++i) {
            const int idx = i * 256 + t;
            const int nr = idx >> 3, ch = (idx & 7) * 8;
            s16x8 o;
#pragma unroll
            for (int e = 0; e < 8; ++e) o[e] = f2bf(sT[ch + e][nr]);
            *(s16x8*)(Wt + (size_t)(n0 + nr) * DIM + k0 + ch) = o;
        }
    } else if (bid < 768) {
        const int vt  = bid - 256;
        const int h   = vt >> 5;
        const int kt0 = (vt & 31) * 64;
        const float* src = vg + ((size_t)h * T_SEQ + kt0) * HD;
#pragma unroll
        for (int i = 0; i < 4; ++i) {
            const int idx = i * 256 + t;
            const int kr = idx >> 4, c4 = (idx & 15) * 4;
            float4 v = *(const float4*)(src + (size_t)kr * HD + c4);
            sT[kr][c4] = v.x; sT[kr][c4 + 1] = v.y; sT[kr][c4 + 2] = v.z; sT[kr][c4 + 3] = v.w;
        }
        __syncthreads();
#pragma unroll
        for (int i = 0; i < 2; ++i) {
            const int idx = i * 256 + t;
            const int nr = idx >> 3, ch = (idx & 7) * 8;
            s16x8 o;
#pragma unroll
            for (int e = 0; e < 8; ++e) o[e] = f2bf(sT[ch + e][nr]);
            *(s16x8*)(Vt + ((size_t)h * HD + nr) * T_SEQ + kt0 + ch) = o;
        }
    } else {
        const int kb = bid - 768;
        const float* src = kg + (size_t)kb * 8192;
        u16* dst = Kc + (size_t)kb * 8192;
#pragma unroll
        for (int i = 0; i < 4; ++i) {
            const int off = i * 2048 + t * 8;
            float4 a = *(const float4*)(src + off);
            float4 b = *(const float4*)(src + off + 4);
            s16x8 o;
            o[0] = f2bf(a.x); o[1] = f2bf(a.y); o[2] = f2bf(a.z); o[3] = f2bf(a.w);
            o[4] = f2bf(b.x); o[5] = f2bf(b.y); o[6] = f2bf(b.z); o[7] = f2bf(b.w);
            *(s16x8*)(dst + off) = o;
        }
    }
}

// ---------------------------------------------------------------------------
// attn: bf16 K/V staged via gload_lds (pre-swizzled source), double-buffered,
// counted vmcnt(4). VALU cuts vs R12 (VALUBusy 46% was the bottleneck):
//  - Q pre-scaled by 0.125*log2e before bf16 -> S is exp2-ready; exp2fast is
//    a single v_exp_f32 (saves 16 v_mul/chunk/thread).
//  - wave-uniform mask specialization: interior chunks (kc>=lo && kc+63<=q0,
//    ~60%) skip the per-element window cmp+sel entirely.
// ---------------------------------------------------------------------------
__global__ __launch_bounds__(256) void attn_kernel(const float* __restrict__ qg,
                                                   const u16* __restrict__ Kc,
                                                   const u16* __restrict__ Vt,
                                                   u16* __restrict__ y) {
    __shared__ __align__(16) char sK[2][8192];   // bf16 [key][d], swz (key&7)<<4
    __shared__ __align__(16) char sV[2][8192];   // bf16 [d][key], swz fV(d)<<4
    __shared__ __align__(16) char sP[4][2048];   // per-wave bf16 P

    const int ab   = (int)blockIdx.x;
    const int swzb = (ab & 7) * 64 + (ab >> 3);   // T1 head-chunking
    const int t    = threadIdx.x;
    const int lane = t & 63;
    const int w    = t >> 6;
    const int q0   = (swzb & 31) * 64;
    const int h    = swzb >> 5;

    const u16* Kh = Kc + (size_t)h * T_SEQ * HD;
    const u16* Vh = Vt + (size_t)h * HD * T_SEQ;

    const int lr = lane & 15;
    const int lg = lane >> 4;

    // Q fragments pre-scaled: S = (Q*scl)K^T, scl = 1/sqrt(64) * log2(e)
    const float SCL = 0.125f * 1.44269504088896f;
    s16x8 qf[2];
    {
        const float* qrow = qg + ((size_t)h * T_SEQ + q0 + w * 16 + lr) * HD + lg * 8;
#pragma unroll
        for (int s = 0; s < 2; ++s) {
            float4 a = *(const float4*)(qrow + 32 * s);
            float4 b = *(const float4*)(qrow + 32 * s + 4);
            s16x8 f;
            f[0] = f2bf(a.x * SCL); f[1] = f2bf(a.y * SCL);
            f[2] = f2bf(a.z * SCL); f[3] = f2bf(a.w * SCL);
            f[4] = f2bf(b.x * SCL); f[5] = f2bf(b.y * SCL);
            f[6] = f2bf(b.z * SCL); f[7] = f2bf(b.w * SCL);
            qf[s] = f;
        }
    }

    f32x4 o[4];
#pragma unroll
    for (int i = 0; i < 4; ++i) o[i] = (f32x4){0.f, 0.f, 0.f, 0.f};
    float lsum[4] = {0.f, 0.f, 0.f, 0.f};

    int lo = q0 - (WIN - 1);
    if (lo < 0) lo = 0;
    const int kc0 = lo & ~63;
    const int nc  = (q0 - kc0) / 64 + 1;

    const int sRow8 = lane >> 3;
    const int sCh   = lane & 7;

#define STAGE(buf, kc)                                                              \
    do {                                                                            \
        _Pragma("unroll") for (int j = 0; j < 2; ++j) {                             \
            const int s_  = j * 4 + w;                                              \
            const int row = s_ * 8 + sRow8;                                         \
            gload16(Kh + (size_t)((kc) + row) * HD + ((sCh ^ (row & 7)) << 3),      \
                    sK[buf] + s_ * 1024);                                           \
            gload16(Vh + (size_t)row * T_SEQ + (kc) + ((sCh ^ fV(row)) << 3),       \
                    sV[buf] + s_ * 1024);                                           \
        }                                                                           \
    } while (0)

    STAGE(0, kc0);

    for (int ic = 0; ic < nc; ++ic) {
        const int kc = kc0 + ic * 64;
        const int cb = ic & 1;
        if (ic + 1 < nc) {
            STAGE(cb ^ 1, kc + 64);
            asm volatile("s_waitcnt vmcnt(4)" ::: "memory");
        } else {
            asm volatile("s_waitcnt vmcnt(0)" ::: "memory");
        }
        __builtin_amdgcn_s_barrier();

        const bool fullValid = (kc >= lo) && (kc + 63 <= q0);  // wave-uniform

        // ---- S = Q K^T (pre-scaled), exp2, P -> per-wave LDS ----
        char* pw = sP[w];
#pragma unroll
        for (int kt = 0; kt < 4; ++kt) {
            const int krow = kt * 16 + lr;
            const int kswz = (krow & 7) << 4;
            s16x8 kf0 = *(const s16x8*)(sK[cb] + krow * 128 + ((lg * 16) ^ kswz));
            s16x8 kf1 = *(const s16x8*)(sK[cb] + krow * 128 + ((lg * 16 + 64) ^ kswz));
            f32x4 s = (f32x4){0.f, 0.f, 0.f, 0.f};
            s = __builtin_amdgcn_mfma_f32_16x16x32_bf16(qf[0], kf0, s, 0, 0, 0);
            s = __builtin_amdgcn_mfma_f32_16x16x32_bf16(qf[1], kf1, s, 0, 0, 0);
            const int key = kc + kt * 16 + lr;
            if (fullValid) {
#pragma unroll
                for (int r = 0; r < 4; ++r) {
                    const float pv = exp2fast(s[r]);
                    lsum[r] += pv;
                    const int prow = lg * 4 + r;
                    *(u16*)(pw + prow * 128 + ((kt * 32 + lr * 2) ^ ((prow & 7) << 4))) = f2bf(pv);
                }
            } else {
#pragma unroll
                for (int r = 0; r < 4; ++r) {
                    const int qrow = q0 + w * 16 + lg * 4 + r;
                    float pv = 0.f;
                    if (key <= qrow && key > qrow - WIN) pv = exp2fast(s[r]);
                    lsum[r] += pv;
                    const int prow = lg * 4 + r;
                    *(u16*)(pw + prow * 128 + ((kt * 32 + lr * 2) ^ ((prow & 7) << 4))) = f2bf(pv);
                }
            }
        }

        // ---- O += P V ----
        s16x8 pf0 = *(const s16x8*)(pw + lr * 128 + ((lg * 16) ^ ((lr & 7) << 4)));
        s16x8 pf1 = *(const s16x8*)(pw + lr * 128 + ((lg * 16 + 64) ^ ((lr & 7) << 4)));
#pragma unroll
        for (int td = 0; td < 4; ++td) {
            const int drow = td * 16 + lr;
            const int vswz = fV(drow) << 4;
            s16x8 vf0 = *(const s16x8*)(sV[cb] + drow * 128 + ((lg * 16) ^ vswz));
            s16x8 vf1 = *(const s16x8*)(sV[cb] + drow * 128 + ((lg * 16 + 64) ^ vswz));
            o[td] = __builtin_amdgcn_mfma_f32_16x16x32_bf16(pf0, vf0, o[td], 0, 0, 0);
            o[td] = __builtin_amdgcn_mfma_f32_16x16x32_bf16(pf1, vf1, o[td], 0, 0, 0);
        }
        __builtin_amdgcn_s_barrier();
    }
#undef STAGE

#pragma unroll
    for (int m = 1; m < 16; m <<= 1) {
#pragma unroll
        for (int r = 0; r < 4; ++r) lsum[r] += __shfl_xor(lsum[r], m, 64);
    }
    float rl[4];
#pragma unroll
    for (int r = 0; r < 4; ++r) rl[r] = 1.f / lsum[r];
#pragma unroll
    for (int td = 0; td < 4; ++td)
#pragma unroll
        for (int r = 0; r < 4; ++r)
            y[(size_t)(q0 + w * 16 + lg * 4 + r) * DIM + h * HD + td * 16 + lr] =
                f2bf(o[td][r] * rl[r]);
}

// ---------------------------------------------------------------------------
// proj: out = y @ W. BM=128 BN=64 BK=64, 4 waves (2x2), wave-tile 64x32.
// DOUBLE-buffered (48KB LDS -> 2 blocks/CU: R12's key finding is that proj is
// per-block latency-bound at 1 block/CU; co-resident blocks give the m114
// implicit overlap). Counted vmcnt(6)-then-barrier; exact 16 tiles staged
// (no stale tail). grid = 256, XCD-chunked swizzle.
// ---------------------------------------------------------------------------
__global__ __launch_bounds__(256) void proj_kernel(const u16* __restrict__ A,
                                                   const u16* __restrict__ Bt,
                                                   float* __restrict__ out) {
    __shared__ __align__(16) char sA[2][128 * 128];  // [m][k] bf16, 16KB/buf
    __shared__ __align__(16) char sB[2][64 * 128];   // [n][k] bf16,  8KB/buf

    const int t    = threadIdx.x;
    const int lane = t & 63;
    const int w    = t >> 6;
    const int wr   = w >> 1, wc = w & 1;
    const int lr   = lane & 15, lg = lane >> 4;

    const int id   = (int)blockIdx.x;
    const int wgid = (id & 7) * 32 + (id >> 3);
    const int m0   = (wgid >> 4) * 128;
    const int n0   = (wgid & 15) * 64;

    f32x4 acc[4][2];
#pragma unroll
    for (int i = 0; i < 4; ++i)
#pragma unroll
        for (int j = 0; j < 2; ++j) acc[i][j] = (f32x4){0.f, 0.f, 0.f, 0.f};

    const int sRow = lane >> 3;
    const int sCh  = lane & 7;

#define STAGE(buf, k0)                                                                 \
    do {                                                                               \
        _Pragma("unroll") for (int p = 0; p < 4; ++p) {                                \
            const int pi  = p * 4 + w;                                                 \
            const int row = pi * 8 + sRow;                                             \
            gload16(A + (size_t)(m0 + row) * DIM + (k0) + ((sCh ^ (row & 7)) << 3),    \
                    sA[buf] + pi * 1024);                                              \
        }                                                                              \
        _Pragma("unroll") for (int p = 0; p < 2; ++p) {                                \
            const int pi  = p * 4 + w;                                                 \
            const int row = pi * 8 + sRow;                                             \
            gload16(Bt + (size_t)(n0 + row) * DIM + (k0) + ((sCh ^ (row & 7)) << 3),   \
                    sB[buf] + pi * 1024);                                              \
        }                                                                              \
    } while (0)

    STAGE(0, 0);

#pragma unroll
    for (int kt = 0; kt < DIM / 64; ++kt) {
        const int cur = kt & 1;
        if (kt + 1 < DIM / 64) {
            STAGE(cur ^ 1, (kt + 1) * 64);   // overwrites buf read at kt-1 (barrier'd)
            asm volatile("s_waitcnt vmcnt(6)" ::: "memory");  // tile-kt landed (own)
        } else {
            asm volatile("s_waitcnt vmcnt(0)" ::: "memory");
        }
        __builtin_amdgcn_s_barrier();        // => ALL waves' tile-kt landed

        s16x8 af[2][4], bfr[2][2];
#pragma unroll
        for (int kh = 0; kh < 2; ++kh) {
#pragma unroll
            for (int mi = 0; mi < 4; ++mi) {
                const int row = wr * 64 + mi * 16 + lr;
                const int cc  = kh * 4 + lg;
                af[kh][mi] = *(const s16x8*)(sA[cur] + row * 128 + ((cc ^ (row & 7)) << 4));
            }
#pragma unroll
            for (int ni = 0; ni < 2; ++ni) {
                const int row = wc * 32 + ni * 16 + lr;
                const int cc  = kh * 4 + lg;
                bfr[kh][ni] = *(const s16x8*)(sB[cur] + row * 128 + ((cc ^ (row & 7)) << 4));
            }
        }
        __builtin_amdgcn_s_setprio(1);
#pragma unroll
        for (int kh = 0; kh < 2; ++kh)
#pragma unroll
            for (int mi = 0; mi < 4; ++mi)
#pragma unroll
                for (int ni = 0; ni < 2; ++ni)
                    acc[mi][ni] = __builtin_amdgcn_mfma_f32_16x16x32_bf16(
                        af[kh][mi], bfr[kh][ni], acc[mi][ni], 0, 0, 0);
        __builtin_amdgcn_s_setprio(0);
        __builtin_amdgcn_s_barrier();        // buf[cur] reads done before overwrite
    }
#undef STAGE

#pragma unroll
    for (int mi = 0; mi < 4; ++mi)
#pragma unroll
        for (int ni = 0; ni < 2; ++ni)
#pragma unroll
            for (int r = 0; r < 4; ++r)
                out[(size_t)(m0 + wr * 64 + mi * 16 + lg * 4 + r) * DIM +
                    n0 + wc * 32 + ni * 16 + lr] = acc[mi][ni][r];
}

extern "C" void kernel_launch(void* const* d_in, const int* in_sizes, int n_in,
                              void* d_out, int out_size, void* d_ws, size_t ws_size,
                              hipStream_t stream) {
    const float* q = (const float*)d_in[0];
    const float* k = (const float*)d_in[1];
    const float* v = (const float*)d_in[2];
    const float* W = (const float*)d_in[3];
    float* out = (float*)d_out;

    u16* y_bf = (u16*)d_ws;                                   // 2M u16 (4MB)
    u16* Wt   = y_bf + (size_t)T_SEQ * DIM;                   // 1M u16 (2MB)
    u16* Kc   = Wt + (size_t)DIM * DIM;                       // 2M u16 (4MB)
    u16* Vt   = Kc + (size_t)NH * T_SEQ * HD;                 // 2M u16 (4MB)

    conv_kernel<<<1024, 256, 0, stream>>>(W, Wt, k, Kc, v, Vt);
    attn_kernel<<<512, 256, 0, stream>>>(q, Kc, Vt, y_bf);
    proj_kernel<<<256, 256, 0, stream>>>(y_bf, Wt, out);
}